// Round 1
// baseline (596.482 us; speedup 1.0000x reference)
//
#include <hip/hip_runtime.h>

#define INV_STD 0.9999950000374997f

typedef unsigned short u16;
typedef __bf16 bf16x8 __attribute__((ext_vector_type(8)));
typedef float f32x4 __attribute__((ext_vector_type(4)));

__device__ __forceinline__ u16 f2bf(float f) {
    unsigned int u = __float_as_uint(f);
    u += 0x7fffu + ((u >> 16) & 1u);   // RNE
    return (u16)(u >> 16);
}
__device__ __forceinline__ float bf2f(u16 h) {
    return __uint_as_float(((unsigned int)h) << 16);
}

// async global->LDS, 16B per lane. LDS dest must be wave-uniform base (HW adds lane*16).
__device__ __forceinline__ void gl_lds16(const void* g, void* l) {
    __builtin_amdgcn_global_load_lds(
        (const __attribute__((address_space(1))) unsigned int*)(unsigned long long)g,
        (__attribute__((address_space(3))) unsigned int*)(unsigned int)(unsigned long long)l,
        16, 0, 0);
}

__device__ __forceinline__ f32x4 mfma16(bf16x8 a, bf16x8 b, f32x4 c) {
    return __builtin_amdgcn_mfma_f32_16x16x32_bf16(a, b, c, 0, 0, 0);
}

// ---------------- weight convert: dst = bf16(W * (INV_STD*gamma[row])) ----------------
__global__ void wconv(const float* __restrict__ W, const float* __restrict__ gamma,
                      u16* __restrict__ dst, int O, int C) {
    long i = (long)blockIdx.x * 256 + threadIdx.x;
    if (i < (long)O * C) {
        int o = (int)(i / C);
        dst[i] = f2bf(W[i] * (INV_STD * gamma[o]));
    }
}

// ---------------- k/v path (tiny): one block per (b,p) proxy pixel ----------------
__global__ __launch_bounds__(256) void kv_kernel(
    const float* __restrict__ proxy,                       // (B,512,19)
    const float* __restrict__ wk1, const float* __restrict__ gk1, const float* __restrict__ bk1,
    const float* __restrict__ wk2, const float* __restrict__ gk2, const float* __restrict__ bk2,
    const float* __restrict__ wv,  const float* __restrict__ gv,  const float* __restrict__ bv,
    float* __restrict__ KT, float* __restrict__ VT)        // (B,19,256) each
{
    int b = blockIdx.x / 19, p = blockIdx.x % 19;
    __shared__ float px[512];
    __shared__ float k1[256];
    int t = threadIdx.x;
    for (int i = t; i < 512; i += 256) px[i] = proxy[((long)b * 512 + i) * 19 + p];
    __syncthreads();
    float aK = 0.f, aV = 0.f;
    const float* wk1r = wk1 + (long)t * 512;
    const float* wvr  = wv  + (long)t * 512;
    #pragma unroll 8
    for (int c = 0; c < 512; ++c) { aK += wk1r[c] * px[c]; aV += wvr[c] * px[c]; }
    float k1v = fmaxf(aK * (INV_STD * gk1[t]) + bk1[t], 0.f);
    float vv  = fmaxf(aV * (INV_STD * gv[t])  + bv[t],  0.f);
    k1[t] = k1v;
    VT[((long)b * 19 + p) * 256 + t] = vv;
    __syncthreads();
    float a2 = 0.f;
    const float* wk2r = wk2 + (long)t * 256;
    #pragma unroll 8
    for (int c = 0; c < 256; ++c) a2 += wk2r[c] * k1[c];
    KT[((long)b * 19 + p) * 256 + t] = fmaxf(a2 * (INV_STD * gk2[t]) + bk2[t], 0.f);
}

// ---------------- transpose+convert: x (B,512,16384) f32 -> xT (B,16384,512) bf16 ----------------
__global__ __launch_bounds__(256) void xpose(const float* __restrict__ X, u16* __restrict__ XT) {
    __shared__ u16 tile[64 * 68];   // [c_local][n_local], pad 4
    int b = blockIdx.z, c0 = blockIdx.y * 64, n0 = blockIdx.x * 64;
    int t = threadIdx.x, tx = t & 15, ty = t >> 4;
    #pragma unroll
    for (int p = 0; p < 4; ++p) {
        int c = ty + p * 16;
        float4 v = *(const float4*)&X[((long)b * 512 + c0 + c) * 16384 + n0 + tx * 4];
        ushort4 u;
        u.x = f2bf(v.x); u.y = f2bf(v.y); u.z = f2bf(v.z); u.w = f2bf(v.w);
        *(ushort4*)&tile[c * 68 + tx * 4] = u;
    }
    __syncthreads();
    #pragma unroll
    for (int p = 0; p < 4; ++p) {
        int n = ty + p * 16;
        ushort4 u;
        u.x = tile[(tx * 4 + 0) * 68 + n];
        u.y = tile[(tx * 4 + 1) * 68 + n];
        u.z = tile[(tx * 4 + 2) * 68 + n];
        u.w = tile[(tx * 4 + 3) * 68 + n];
        *(ushort4*)&XT[((long)b * 16384 + n0 + n) * 512 + c0 + tx * 4] = u;
    }
}

// ---------------- GEMM (pixel-major): out[pix][ch] = relu( A[pix,:]·W[ch,:] + bias[ch] ), N=256 ----------------
// BM=64, BN=256, BK=64, 4 waves. A: (M,K) bf16 K-contig. W: (256,K) bf16. out: (M,256) bf16.
__global__ __launch_bounds__(256) void gemm_a(const u16* __restrict__ A, const u16* __restrict__ W,
                                              const float* __restrict__ bias, u16* __restrict__ out,
                                              int K) {
    __shared__ __align__(16) u16 lA[64 * 64];
    __shared__ __align__(16) u16 lB[256 * 64];
    int t = threadIdx.x, lane = t & 63, w = t >> 6;
    int l16 = lane & 15, hi = lane >> 4;
    long m0 = (long)blockIdx.x * 64;
    int rA = lane >> 3, cA = (lane & 7) << 3;
    f32x4 acc[4][4] = {};
    int nkt = K >> 6;
    for (int kt = 0; kt < nkt; ++kt) {
        int k0 = kt << 6;
        #pragma unroll
        for (int j = 0; j < 2; ++j) {            // A tile: 64x64
            int q = w * 2 + j;
            gl_lds16(A + (m0 + q * 8 + rA) * (long)K + k0 + cA, &lA[q * 512]);
        }
        #pragma unroll
        for (int j = 0; j < 8; ++j) {            // W tile: 256x64
            int q = w * 8 + j;
            gl_lds16(W + (long)(q * 8 + rA) * K + k0 + cA, &lB[q * 512]);
        }
        __syncthreads();
        #pragma unroll
        for (int kk = 0; kk < 2; ++kk) {
            bf16x8 a[4], bb[4];
            #pragma unroll
            for (int i = 0; i < 4; ++i)
                a[i] = *(const bf16x8*)&lA[(i * 16 + l16) * 64 + kk * 32 + hi * 8];
            #pragma unroll
            for (int j = 0; j < 4; ++j)
                bb[j] = *(const bf16x8*)&lB[(w * 64 + j * 16 + l16) * 64 + kk * 32 + hi * 8];
            #pragma unroll
            for (int i = 0; i < 4; ++i)
                #pragma unroll
                for (int j = 0; j < 4; ++j)
                    acc[i][j] = mfma16(a[i], bb[j], acc[i][j]);
        }
        __syncthreads();
    }
    float bj[4];
    #pragma unroll
    for (int j = 0; j < 4; ++j) bj[j] = bias[w * 64 + j * 16 + l16];
    #pragma unroll
    for (int i = 0; i < 4; ++i) {
        #pragma unroll
        for (int r = 0; r < 4; ++r) {
            long pix = m0 + i * 16 + hi * 4 + r;
            u16* orow = out + pix * 256;
            #pragma unroll
            for (int j = 0; j < 4; ++j) {
                float v = acc[i][j][r] + bj[j];
                orow[w * 64 + j * 16 + l16] = f2bf(fmaxf(v, 0.f));
            }
        }
    }
}

// ---------------- attention: per pixel, sim(19)=q2·k/16, softmax, ctx = att·v ----------------
__global__ __launch_bounds__(256) void attn_kernel(const u16* __restrict__ Q2,
                                                   const float* __restrict__ KT,
                                                   const float* __restrict__ VT,
                                                   u16* __restrict__ CTX) {
    __shared__ float kS[19 * 256];
    __shared__ float vS[19 * 256];
    int t = threadIdx.x;
    int b = blockIdx.y;
    for (int i = t; i < 19 * 256; i += 256) {
        kS[i] = KT[(long)b * 4864 + i];
        vS[i] = VT[(long)b * 4864 + i];
    }
    __syncthreads();
    int g = t >> 4, j = t & 15;
    int base = blockIdx.x * 256;
    for (int pass = 0; pass < 16; ++pass) {
        int n = base + pass * 16 + g;
        const u16* qrow = Q2 + ((long)b * 16384 + n) * 256;
        float qv[16];
        #pragma unroll
        for (int i = 0; i < 16; ++i) qv[i] = bf2f(qrow[j + 16 * i]);
        float sim[19];
        #pragma unroll
        for (int p = 0; p < 19; ++p) {
            float s = 0.f;
            #pragma unroll
            for (int i = 0; i < 16; ++i) s += qv[i] * kS[p * 256 + j + 16 * i];
            s += __shfl_xor(s, 1);
            s += __shfl_xor(s, 2);
            s += __shfl_xor(s, 4);
            s += __shfl_xor(s, 8);
            sim[p] = s * 0.0625f;
        }
        float m = sim[0];
        #pragma unroll
        for (int p = 1; p < 19; ++p) m = fmaxf(m, sim[p]);
        float sum = 0.f;
        #pragma unroll
        for (int p = 0; p < 19; ++p) { sim[p] = __expf(sim[p] - m); sum += sim[p]; }
        float inv = 1.f / sum;
        u16* crow = CTX + ((long)b * 16384 + n) * 256;
        #pragma unroll
        for (int i = 0; i < 16; ++i) {
            float c = 0.f;
            #pragma unroll
            for (int p = 0; p < 19; ++p) c += sim[p] * vS[p * 256 + j + 16 * i];
            crow[j + 16 * i] = f2bf(c * inv);
        }
    }
}

// ---------------- final GEMM: out[b][ch][pix] = relu( wo[ch,:]·ctx[pix,:] + bo[ch] ) ----------------
// BM=256 (channels), BN=128 (pixels), BK=64, 8 waves (4x2).
__global__ __launch_bounds__(512) void gemm_out(const u16* __restrict__ Wo,   // (512,256) bf16
                                                const u16* __restrict__ Ctx, // (B*HW,256) bf16
                                                const float* __restrict__ bias,
                                                float* __restrict__ out) {
    __shared__ __align__(16) u16 lA[256 * 64];
    __shared__ __align__(16) u16 lB[128 * 64];
    int t = threadIdx.x, lane = t & 63, w = t >> 6;
    int wm = w >> 1, wn = w & 1;
    int l16 = lane & 15, hi = lane >> 4;
    int m0 = blockIdx.y * 256;
    int n0 = blockIdx.x * 128;
    int b = blockIdx.z;
    const int K = 256;
    int rA = lane >> 3, cA = (lane & 7) << 3;
    f32x4 acc[4][4] = {};
    #pragma unroll
    for (int kt = 0; kt < 4; ++kt) {
        int k0 = kt << 6;
        #pragma unroll
        for (int j = 0; j < 4; ++j) {            // Wo tile: 256x64
            int q = w * 4 + j;
            gl_lds16(Wo + (long)(m0 + q * 8 + rA) * K + k0 + cA, &lA[q * 512]);
        }
        #pragma unroll
        for (int j = 0; j < 2; ++j) {            // ctx tile: 128x64
            int q = w * 2 + j;
            gl_lds16(Ctx + ((long)b * 16384 + n0 + q * 8 + rA) * K + k0 + cA, &lB[q * 512]);
        }
        __syncthreads();
        #pragma unroll
        for (int kk = 0; kk < 2; ++kk) {
            bf16x8 a[4], bb[4];
            #pragma unroll
            for (int i = 0; i < 4; ++i)
                a[i] = *(const bf16x8*)&lA[(wm * 64 + i * 16 + l16) * 64 + kk * 32 + hi * 8];
            #pragma unroll
            for (int j = 0; j < 4; ++j)
                bb[j] = *(const bf16x8*)&lB[(wn * 64 + j * 16 + l16) * 64 + kk * 32 + hi * 8];
            #pragma unroll
            for (int i = 0; i < 4; ++i)
                #pragma unroll
                for (int j = 0; j < 4; ++j)
                    acc[i][j] = mfma16(a[i], bb[j], acc[i][j]);
        }
        __syncthreads();
    }
    #pragma unroll
    for (int i = 0; i < 4; ++i) {
        #pragma unroll
        for (int r = 0; r < 4; ++r) {
            int ch = m0 + wm * 64 + i * 16 + hi * 4 + r;
            float bc = bias[ch];
            float* orow = out + ((long)b * 512 + ch) * 16384;
            #pragma unroll
            for (int j = 0; j < 4; ++j) {
                int pix = n0 + wn * 64 + j * 16 + l16;
                float v = acc[i][j][r] + bc;
                orow[pix] = fmaxf(v, 0.f);
            }
        }
    }
}

extern "C" void kernel_launch(void* const* d_in, const int* in_sizes, int n_in,
                              void* d_out, int out_size, void* d_ws, size_t ws_size,
                              hipStream_t stream) {
    const float* x    = (const float*)d_in[0];
    const float* prox = (const float*)d_in[1];
    const float* wq1  = (const float*)d_in[2];
    const float* gq1  = (const float*)d_in[3];
    const float* bq1  = (const float*)d_in[4];
    const float* wq2  = (const float*)d_in[5];
    const float* gq2  = (const float*)d_in[6];
    const float* bq2  = (const float*)d_in[7];
    const float* wk1  = (const float*)d_in[8];
    const float* gk1  = (const float*)d_in[9];
    const float* bk1  = (const float*)d_in[10];
    const float* wk2  = (const float*)d_in[11];
    const float* gk2  = (const float*)d_in[12];
    const float* bk2  = (const float*)d_in[13];
    const float* wv   = (const float*)d_in[14];
    const float* gv   = (const float*)d_in[15];
    const float* bv   = (const float*)d_in[16];
    const float* wo   = (const float*)d_in[17];
    const float* go   = (const float*)d_in[18];
    const float* bo   = (const float*)d_in[19];
    float* out = (float*)d_out;

    char* ws = (char*)d_ws;
    // xT: [0, 128MB)  (aliased later by q2)
    // q1: [128MB, 192MB)  (aliased later by ctx)
    u16* XT  = (u16*)(ws);
    u16* Q2  = (u16*)(ws);                       // overwrites xT after GEMM1 is done
    u16* Q1  = (u16*)(ws + 134217728LL);
    u16* CTX = (u16*)(ws + 134217728LL);         // overwrites q1 after GEMM2 is done
    float* KT = (float*)(ws + 201326592LL);
    float* VT = KT + 38912;                      // 8*19*256
    u16* WQ1B = (u16*)(ws + 201326592LL + 311296LL);
    u16* WQ2B = WQ1B + 131072;
    u16* WOB  = WQ2B + 65536;

    wconv<<<512, 256, 0, stream>>>(wq1, gq1, WQ1B, 256, 512);
    wconv<<<256, 256, 0, stream>>>(wq2, gq2, WQ2B, 256, 256);
    wconv<<<512, 256, 0, stream>>>(wo,  go,  WOB, 512, 256);
    kv_kernel<<<152, 256, 0, stream>>>(prox, wk1, gk1, bk1, wk2, gk2, bk2, wv, gv, bv, KT, VT);
    xpose<<<dim3(256, 8, 8), 256, 0, stream>>>(x, XT);
    gemm_a<<<2048, 256, 0, stream>>>(XT, WQ1B, bq1, Q1, 512);
    gemm_a<<<2048, 256, 0, stream>>>(Q1, WQ2B, bq2, Q2, 256);
    attn_kernel<<<dim3(64, 8), 256, 0, stream>>>(Q2, KT, VT, CTX);
    gemm_out<<<dim3(128, 2, 8), 512, 0, stream>>>(WOB, CTX, bo, out);
}

// Round 2
// 360.374 us; speedup vs baseline: 1.6552x; 1.6552x over previous
//
#include <hip/hip_runtime.h>

#define INV_STD 0.9999950000374997f

typedef unsigned short u16;
typedef __bf16 bf16x8 __attribute__((ext_vector_type(8)));
typedef float f32x4 __attribute__((ext_vector_type(4)));

__device__ __forceinline__ u16 f2bf(float f) {
    unsigned int u = __float_as_uint(f);
    u += 0x7fffu + ((u >> 16) & 1u);   // RNE
    return (u16)(u >> 16);
}
__device__ __forceinline__ float bf2f(u16 h) {
    return __uint_as_float(((unsigned int)h) << 16);
}

// async global->LDS, 16B per lane. LDS dest must be wave-uniform base (HW adds lane*16).
__device__ __forceinline__ void gl_lds16(const void* g, void* l) {
    __builtin_amdgcn_global_load_lds(
        (const __attribute__((address_space(1))) unsigned int*)(unsigned long long)g,
        (__attribute__((address_space(3))) unsigned int*)(unsigned int)(unsigned long long)l,
        16, 0, 0);
}

__device__ __forceinline__ f32x4 mfma16(bf16x8 a, bf16x8 b, f32x4 c) {
    return __builtin_amdgcn_mfma_f32_16x16x32_bf16(a, b, c, 0, 0, 0);
}

// ---------------- weight convert: dst = bf16(W * (INV_STD*gamma[row])) ----------------
__global__ void wconv(const float* __restrict__ W, const float* __restrict__ gamma,
                      u16* __restrict__ dst, int O, int C) {
    long i = (long)blockIdx.x * 256 + threadIdx.x;
    if (i < (long)O * C) {
        int o = (int)(i / C);
        dst[i] = f2bf(W[i] * (INV_STD * gamma[o]));
    }
}

// ---------------- k/v path (tiny): one block per (b,p); p in [0,32) with zero-padding ----------------
__global__ __launch_bounds__(256) void kv_kernel(
    const float* __restrict__ proxy,                       // (B,512,19)
    const float* __restrict__ wk1, const float* __restrict__ gk1, const float* __restrict__ bk1,
    const float* __restrict__ wk2, const float* __restrict__ gk2, const float* __restrict__ bk2,
    const float* __restrict__ wv,  const float* __restrict__ gv,  const float* __restrict__ bv,
    u16* __restrict__ KB,                                  // (B,32,256) bf16, rows 19..31 zero
    u16* __restrict__ VB)                                  // (B,256,32) bf16, cols 19..31 zero
{
    int b = blockIdx.x >> 5, p = blockIdx.x & 31;
    int t = threadIdx.x;
    if (p >= 19) {   // zero padding (p uniform per block -> uniform return, no barrier issues)
        KB[((long)b * 32 + p) * 256 + t] = 0;
        VB[((long)b * 256 + t) * 32 + p] = 0;
        return;
    }
    __shared__ float px[512];
    __shared__ float k1[256];
    for (int i = t; i < 512; i += 256) px[i] = proxy[((long)b * 512 + i) * 19 + p];
    __syncthreads();
    float aK = 0.f, aV = 0.f;
    const float* wk1r = wk1 + (long)t * 512;
    const float* wvr  = wv  + (long)t * 512;
    #pragma unroll 8
    for (int c = 0; c < 512; ++c) { aK += wk1r[c] * px[c]; aV += wvr[c] * px[c]; }
    float k1v = fmaxf(aK * (INV_STD * gk1[t]) + bk1[t], 0.f);
    float vv  = fmaxf(aV * (INV_STD * gv[t])  + bv[t],  0.f);
    k1[t] = k1v;
    VB[((long)b * 256 + t) * 32 + p] = f2bf(vv);
    __syncthreads();
    float a2 = 0.f;
    const float* wk2r = wk2 + (long)t * 256;
    #pragma unroll 8
    for (int c = 0; c < 256; ++c) a2 += wk2r[c] * k1[c];
    KB[((long)b * 32 + p) * 256 + t] = f2bf(fmaxf(a2 * (INV_STD * gk2[t]) + bk2[t], 0.f));
}

// ---------------- transpose+convert: x (B,512,16384) f32 -> xT (B,16384,512) bf16 ----------------
__global__ __launch_bounds__(256) void xpose(const float* __restrict__ X, u16* __restrict__ XT) {
    __shared__ u16 tile[64 * 68];   // [c_local][n_local], pad 4
    int b = blockIdx.z, c0 = blockIdx.y * 64, n0 = blockIdx.x * 64;
    int t = threadIdx.x, tx = t & 15, ty = t >> 4;
    #pragma unroll
    for (int p = 0; p < 4; ++p) {
        int c = ty + p * 16;
        float4 v = *(const float4*)&X[((long)b * 512 + c0 + c) * 16384 + n0 + tx * 4];
        ushort4 u;
        u.x = f2bf(v.x); u.y = f2bf(v.y); u.z = f2bf(v.z); u.w = f2bf(v.w);
        *(ushort4*)&tile[c * 68 + tx * 4] = u;
    }
    __syncthreads();
    #pragma unroll
    for (int p = 0; p < 4; ++p) {
        int n = ty + p * 16;
        ushort4 u;
        u.x = tile[(tx * 4 + 0) * 68 + n];
        u.y = tile[(tx * 4 + 1) * 68 + n];
        u.z = tile[(tx * 4 + 2) * 68 + n];
        u.w = tile[(tx * 4 + 3) * 68 + n];
        *(ushort4*)&XT[((long)b * 16384 + n0 + n) * 512 + c0 + tx * 4] = u;
    }
}

// ---------------- GEMM1 (pixel-major): out[pix][ch] = relu( A[pix,:]·W[ch,:] + bias[ch] ), N=256 ----------------
// BM=64, BN=256, BK=64, 4 waves.
__global__ __launch_bounds__(256) void gemm_a(const u16* __restrict__ A, const u16* __restrict__ W,
                                              const float* __restrict__ bias, u16* __restrict__ out,
                                              int K) {
    __shared__ __align__(16) u16 lA[64 * 64];
    __shared__ __align__(16) u16 lB[256 * 64];
    int t = threadIdx.x, lane = t & 63, w = t >> 6;
    int l16 = lane & 15, hi = lane >> 4;
    long m0 = (long)blockIdx.x * 64;
    int rA = lane >> 3, cA = (lane & 7) << 3;
    f32x4 acc[4][4] = {};
    int nkt = K >> 6;
    for (int kt = 0; kt < nkt; ++kt) {
        int k0 = kt << 6;
        #pragma unroll
        for (int j = 0; j < 2; ++j) {
            int q = w * 2 + j;
            gl_lds16(A + (m0 + q * 8 + rA) * (long)K + k0 + cA, &lA[q * 512]);
        }
        #pragma unroll
        for (int j = 0; j < 8; ++j) {
            int q = w * 8 + j;
            gl_lds16(W + (long)(q * 8 + rA) * K + k0 + cA, &lB[q * 512]);
        }
        __syncthreads();
        #pragma unroll
        for (int kk = 0; kk < 2; ++kk) {
            bf16x8 a[4], bb[4];
            #pragma unroll
            for (int i = 0; i < 4; ++i)
                a[i] = *(const bf16x8*)&lA[(i * 16 + l16) * 64 + kk * 32 + hi * 8];
            #pragma unroll
            for (int j = 0; j < 4; ++j)
                bb[j] = *(const bf16x8*)&lB[(w * 64 + j * 16 + l16) * 64 + kk * 32 + hi * 8];
            #pragma unroll
            for (int i = 0; i < 4; ++i)
                #pragma unroll
                for (int j = 0; j < 4; ++j)
                    acc[i][j] = mfma16(a[i], bb[j], acc[i][j]);
        }
        __syncthreads();
    }
    float bj[4];
    #pragma unroll
    for (int j = 0; j < 4; ++j) bj[j] = bias[w * 64 + j * 16 + l16];
    #pragma unroll
    for (int i = 0; i < 4; ++i) {
        #pragma unroll
        for (int r = 0; r < 4; ++r) {
            long pix = m0 + i * 16 + hi * 4 + r;
            u16* orow = out + pix * 256;
            #pragma unroll
            for (int j = 0; j < 4; ++j) {
                float v = acc[i][j][r] + bj[j];
                orow[w * 64 + j * 16 + l16] = f2bf(fmaxf(v, 0.f));
            }
        }
    }
}

// ---------------- fused GEMM2 + attention ----------------
// Per block: 64 pixels. q2 = relu(q1·W2 + b2) -> LDS; sim = q2·KB^T (MFMA); softmax; ctx = att·VB^T (MFMA).
__global__ __launch_bounds__(256) void gemm2_attn(
    const u16* __restrict__ A,      // Q1 (B*HW, 256) bf16
    const u16* __restrict__ W,      // W2 (256,256) bf16 (BN-folded)
    const float* __restrict__ bias, // bq2
    const u16* __restrict__ KB,     // (B,32,256) bf16
    const u16* __restrict__ VB,     // (B,256,32) bf16
    u16* __restrict__ CTX)          // (B*HW,256) bf16
{
    __shared__ __align__(16) u16 lA[64 * 64];     //  8 KB
    __shared__ __align__(16) u16 lB[256 * 64];    // 32 KB
    __shared__ __align__(16) u16 q2s[64 * 264];   // 33.8 KB, row stride 264 u16 (528B, 16B-aligned, bank-spread)
    __shared__ __align__(16) u16 atts[64 * 40];   //  5.1 KB, row stride 40 u16 (80B)
    int t = threadIdx.x, lane = t & 63, w = t >> 6;
    int l16 = lane & 15, hi = lane >> 4;
    long m0 = (long)blockIdx.x * 64;
    int b = (int)(m0 >> 14);                      // 16384 pixels per image
    const int K = 256;
    int rA = lane >> 3, cA = (lane & 7) << 3;
    f32x4 acc[4][4] = {};
    // ---- main GEMM2: q2 = q1 · W2^T ----
    #pragma unroll
    for (int kt = 0; kt < 4; ++kt) {
        int k0 = kt << 6;
        #pragma unroll
        for (int j = 0; j < 2; ++j) {
            int q = w * 2 + j;
            gl_lds16(A + (m0 + q * 8 + rA) * (long)K + k0 + cA, &lA[q * 512]);
        }
        #pragma unroll
        for (int j = 0; j < 8; ++j) {
            int q = w * 8 + j;
            gl_lds16(W + (long)(q * 8 + rA) * K + k0 + cA, &lB[q * 512]);
        }
        __syncthreads();
        #pragma unroll
        for (int kk = 0; kk < 2; ++kk) {
            bf16x8 a[4], bb[4];
            #pragma unroll
            for (int i = 0; i < 4; ++i)
                a[i] = *(const bf16x8*)&lA[(i * 16 + l16) * 64 + kk * 32 + hi * 8];
            #pragma unroll
            for (int j = 0; j < 4; ++j)
                bb[j] = *(const bf16x8*)&lB[(w * 64 + j * 16 + l16) * 64 + kk * 32 + hi * 8];
            #pragma unroll
            for (int i = 0; i < 4; ++i)
                #pragma unroll
                for (int j = 0; j < 4; ++j)
                    acc[i][j] = mfma16(a[i], bb[j], acc[i][j]);
        }
        __syncthreads();
    }
    // ---- epilogue: relu+bias, q2 -> LDS (pixel-row-major, A-frag friendly) ----
    {
        float bj[4];
        #pragma unroll
        for (int j = 0; j < 4; ++j) bj[j] = bias[w * 64 + j * 16 + l16];
        #pragma unroll
        for (int i = 0; i < 4; ++i)
            #pragma unroll
            for (int r = 0; r < 4; ++r) {
                int pix = i * 16 + hi * 4 + r;
                #pragma unroll
                for (int j = 0; j < 4; ++j) {
                    float v = acc[i][j][r] + bj[j];
                    q2s[pix * 264 + w * 64 + j * 16 + l16] = f2bf(fmaxf(v, 0.f));
                }
            }
    }
    __syncthreads();
    // ---- sim = q2 · KB^T : wave w handles pixels w*16..w*16+15 ----
    f32x4 s0 = {}, s1 = {};
    #pragma unroll
    for (int ks = 0; ks < 8; ++ks) {
        bf16x8 a = *(const bf16x8*)&q2s[(w * 16 + l16) * 264 + ks * 32 + hi * 8];
        bf16x8 b0 = *(const bf16x8*)&KB[((long)b * 32 + l16) * 256 + ks * 32 + hi * 8];
        bf16x8 b1 = *(const bf16x8*)&KB[((long)b * 32 + 16 + l16) * 256 + ks * 32 + hi * 8];
        s0 = mfma16(a, b0, s0);
        s1 = mfma16(a, b1, s1);
    }
    // ---- softmax over p (19 valid; pads give sim=0, all real sims >= 0) ----
    {
        const float scale = 0.0625f;   // 256^-0.5
        #pragma unroll
        for (int r = 0; r < 4; ++r) {
            float v0 = s0[r] * scale;
            float v1 = s1[r] * scale;
            float mx = fmaxf(v0, v1);
            mx = fmaxf(mx, __shfl_xor(mx, 1));
            mx = fmaxf(mx, __shfl_xor(mx, 2));
            mx = fmaxf(mx, __shfl_xor(mx, 4));
            mx = fmaxf(mx, __shfl_xor(mx, 8));
            float e0 = __expf(v0 - mx);
            float e1 = (l16 < 3) ? __expf(v1 - mx) : 0.f;   // p = 16+l16 valid only for p<19
            float s = e0 + e1;
            s += __shfl_xor(s, 1);
            s += __shfl_xor(s, 2);
            s += __shfl_xor(s, 4);
            s += __shfl_xor(s, 8);
            float inv = 1.f / s;
            int pix = w * 16 + hi * 4 + r;
            atts[pix * 40 + l16] = f2bf(e0 * inv);
            atts[pix * 40 + 16 + l16] = (l16 < 3) ? f2bf(e1 * inv) : (u16)0;
        }
    }
    __syncthreads();
    // ---- ctx = att · VB^T : wave w owns channels w*64..+63, all 64 pixels ----
    {
        f32x4 c4[4][4] = {};
        bf16x8 av[4], bv[4];
        #pragma unroll
        for (int mf = 0; mf < 4; ++mf)
            av[mf] = *(const bf16x8*)&atts[(mf * 16 + l16) * 40 + hi * 8];
        #pragma unroll
        for (int nf = 0; nf < 4; ++nf)
            bv[nf] = *(const bf16x8*)&VB[((long)b * 256 + w * 64 + nf * 16 + l16) * 32 + hi * 8];
        #pragma unroll
        for (int mf = 0; mf < 4; ++mf)
            #pragma unroll
            for (int nf = 0; nf < 4; ++nf)
                c4[mf][nf] = mfma16(av[mf], bv[nf], c4[mf][nf]);
        #pragma unroll
        for (int mf = 0; mf < 4; ++mf) {
            #pragma unroll
            for (int r = 0; r < 4; ++r) {
                long pix = m0 + mf * 16 + hi * 4 + r;
                u16* crow = CTX + pix * 256;
                #pragma unroll
                for (int nf = 0; nf < 4; ++nf)
                    crow[w * 64 + nf * 16 + l16] = f2bf(c4[mf][nf][r]);
            }
        }
    }
}

// ---------------- final GEMM: out[b][ch][pix] = relu( wo[ch,:]·ctx[pix,:] + bo[ch] ) ----------------
__global__ __launch_bounds__(512) void gemm_out(const u16* __restrict__ Wo,   // (512,256) bf16
                                                const u16* __restrict__ Ctx, // (B*HW,256) bf16
                                                const float* __restrict__ bias,
                                                float* __restrict__ out) {
    __shared__ __align__(16) u16 lA[256 * 64];
    __shared__ __align__(16) u16 lB[128 * 64];
    int t = threadIdx.x, lane = t & 63, w = t >> 6;
    int wm = w >> 1, wn = w & 1;
    int l16 = lane & 15, hi = lane >> 4;
    int m0 = blockIdx.y * 256;
    int n0 = blockIdx.x * 128;
    int b = blockIdx.z;
    const int K = 256;
    int rA = lane >> 3, cA = (lane & 7) << 3;
    f32x4 acc[4][4] = {};
    #pragma unroll
    for (int kt = 0; kt < 4; ++kt) {
        int k0 = kt << 6;
        #pragma unroll
        for (int j = 0; j < 4; ++j) {
            int q = w * 4 + j;
            gl_lds16(Wo + (long)(m0 + q * 8 + rA) * K + k0 + cA, &lA[q * 512]);
        }
        #pragma unroll
        for (int j = 0; j < 2; ++j) {
            int q = w * 2 + j;
            gl_lds16(Ctx + ((long)b * 16384 + n0 + q * 8 + rA) * K + k0 + cA, &lB[q * 512]);
        }
        __syncthreads();
        #pragma unroll
        for (int kk = 0; kk < 2; ++kk) {
            bf16x8 a[4], bb[4];
            #pragma unroll
            for (int i = 0; i < 4; ++i)
                a[i] = *(const bf16x8*)&lA[(wm * 64 + i * 16 + l16) * 64 + kk * 32 + hi * 8];
            #pragma unroll
            for (int j = 0; j < 4; ++j)
                bb[j] = *(const bf16x8*)&lB[(wn * 64 + j * 16 + l16) * 64 + kk * 32 + hi * 8];
            #pragma unroll
            for (int i = 0; i < 4; ++i)
                #pragma unroll
                for (int j = 0; j < 4; ++j)
                    acc[i][j] = mfma16(a[i], bb[j], acc[i][j]);
        }
        __syncthreads();
    }
    #pragma unroll
    for (int i = 0; i < 4; ++i) {
        #pragma unroll
        for (int r = 0; r < 4; ++r) {
            int ch = m0 + wm * 64 + i * 16 + hi * 4 + r;
            float bc = bias[ch];
            float* orow = out + ((long)b * 512 + ch) * 16384;
            #pragma unroll
            for (int j = 0; j < 4; ++j) {
                int pix = n0 + wn * 64 + j * 16 + l16;
                float v = acc[i][j][r] + bc;
                orow[pix] = fmaxf(v, 0.f);
            }
        }
    }
}

extern "C" void kernel_launch(void* const* d_in, const int* in_sizes, int n_in,
                              void* d_out, int out_size, void* d_ws, size_t ws_size,
                              hipStream_t stream) {
    const float* x    = (const float*)d_in[0];
    const float* prox = (const float*)d_in[1];
    const float* wq1  = (const float*)d_in[2];
    const float* gq1  = (const float*)d_in[3];
    const float* bq1  = (const float*)d_in[4];
    const float* wq2  = (const float*)d_in[5];
    const float* gq2  = (const float*)d_in[6];
    const float* bq2  = (const float*)d_in[7];
    const float* wk1  = (const float*)d_in[8];
    const float* gk1  = (const float*)d_in[9];
    const float* bk1  = (const float*)d_in[10];
    const float* wk2  = (const float*)d_in[11];
    const float* gk2  = (const float*)d_in[12];
    const float* bk2  = (const float*)d_in[13];
    const float* wv   = (const float*)d_in[14];
    const float* gv   = (const float*)d_in[15];
    const float* bv   = (const float*)d_in[16];
    const float* wo   = (const float*)d_in[17];
    const float* go   = (const float*)d_in[18];
    const float* bo   = (const float*)d_in[19];
    float* out = (float*)d_out;

    char* ws = (char*)d_ws;
    // XT: [0,128MB) read by gemm1; dead afterwards -> CTX aliases it.
    // Q1: [128MB,192MB) read by gemm2_attn.
    u16* XT  = (u16*)(ws);
    u16* CTX = (u16*)(ws);                       // overwrites XT after gemm1
    u16* Q1  = (u16*)(ws + 134217728LL);
    u16* KB  = (u16*)(ws + 201326592LL);         // 8*32*256 bf16 = 128KB
    u16* VB  = KB + 65536;                       // 8*256*32 bf16 = 128KB
    u16* WQ1B = VB + 65536;
    u16* WQ2B = WQ1B + 131072;
    u16* WOB  = WQ2B + 65536;

    wconv<<<512, 256, 0, stream>>>(wq1, gq1, WQ1B, 256, 512);
    wconv<<<256, 256, 0, stream>>>(wq2, gq2, WQ2B, 256, 256);
    wconv<<<512, 256, 0, stream>>>(wo,  go,  WOB, 512, 256);
    kv_kernel<<<256, 256, 0, stream>>>(prox, wk1, gk1, bk1, wk2, gk2, bk2, wv, gv, bv, KB, VB);
    xpose<<<dim3(256, 8, 8), 256, 0, stream>>>(x, XT);
    gemm_a<<<2048, 256, 0, stream>>>(XT, WQ1B, bq1, Q1, 512);
    gemm2_attn<<<2048, 256, 0, stream>>>(Q1, WQ2B, bq2, KB, VB, CTX);
    gemm_out<<<dim3(128, 2, 8), 512, 0, stream>>>(WOB, CTX, bo, out);
}

// Round 3
// 291.783 us; speedup vs baseline: 2.0443x; 1.2351x over previous
//
#include <hip/hip_runtime.h>

#define INV_STD 0.9999950000374997f

typedef unsigned short u16;
typedef __bf16 bf16x8 __attribute__((ext_vector_type(8)));
typedef __bf16 bf16x4 __attribute__((ext_vector_type(4)));
typedef float f32x4 __attribute__((ext_vector_type(4)));

__device__ __forceinline__ u16 f2bf(float f) {
    unsigned int u = __float_as_uint(f);
    u += 0x7fffu + ((u >> 16) & 1u);   // RNE
    return (u16)(u >> 16);
}
__device__ __forceinline__ float bf2f(u16 h) {
    return __uint_as_float(((unsigned int)h) << 16);
}

// async global->LDS, 16B per lane. LDS dest must be wave-uniform base (HW adds lane*16).
__device__ __forceinline__ void gl_lds16(const void* g, void* l) {
    __builtin_amdgcn_global_load_lds(
        (const __attribute__((address_space(1))) unsigned int*)(unsigned long long)g,
        (__attribute__((address_space(3))) unsigned int*)(unsigned int)(unsigned long long)l,
        16, 0, 0);
}

__device__ __forceinline__ f32x4 mfma16(bf16x8 a, bf16x8 b, f32x4 c) {
    return __builtin_amdgcn_mfma_f32_16x16x32_bf16(a, b, c, 0, 0, 0);
}

__device__ __forceinline__ unsigned lds_off(const void* p) {
    return (unsigned)(unsigned long long)p;
}

// hardware transpose read: lane reads 4 bf16 at byte addr +0,+32,+64,+96
__device__ __forceinline__ bf16x4 tr_read(unsigned addr) {
    bf16x4 r;
    asm volatile("ds_read_b64_tr_b16 %0, %1" : "=v"(r) : "v"(addr));
    return r;
}

// ---------------- weight convert: dst = bf16(W * (INV_STD*gamma[row])) ----------------
__global__ void wconv(const float* __restrict__ W, const float* __restrict__ gamma,
                      u16* __restrict__ dst, int O, int C) {
    long i = (long)blockIdx.x * 256 + threadIdx.x;
    if (i < (long)O * C) {
        int o = (int)(i / C);
        dst[i] = f2bf(W[i] * (INV_STD * gamma[o]));
    }
}

// ---------------- weight convert + K-permute (sigma within each 32-group), C=512 ----------------
// sigma(r) = hi*4 + (e&3) + 16*(e>>2), r = hi*8+e  -- matches tr-read channel order in gemm1_x
__global__ void wconv_perm(const float* __restrict__ W, const float* __restrict__ gamma,
                           u16* __restrict__ dst) {
    long i = (long)blockIdx.x * 256 + threadIdx.x;   // 256*512 total
    int o = (int)(i >> 9);
    int q = (int)(i & 511);
    int r = q & 31;
    int src = (q & ~31) + ((r >> 3) & 3) * 4 + (r & 3) + ((r >> 2) & 1) * 16;
    dst[i] = f2bf(W[(long)o * 512 + src] * (INV_STD * gamma[o]));
}

// ---------------- k/v path (tiny): one block per (b,p); p in [0,32) with zero-padding ----------------
__global__ __launch_bounds__(256) void kv_kernel(
    const float* __restrict__ proxy,                       // (B,512,19)
    const float* __restrict__ wk1, const float* __restrict__ gk1, const float* __restrict__ bk1,
    const float* __restrict__ wk2, const float* __restrict__ gk2, const float* __restrict__ bk2,
    const float* __restrict__ wv,  const float* __restrict__ gv,  const float* __restrict__ bv,
    u16* __restrict__ KB,                                  // (B,32,256) bf16, rows 19..31 zero
    u16* __restrict__ VB)                                  // (B,256,32) bf16, cols 19..31 zero
{
    int b = blockIdx.x >> 5, p = blockIdx.x & 31;
    int t = threadIdx.x;
    if (p >= 19) {
        KB[((long)b * 32 + p) * 256 + t] = 0;
        VB[((long)b * 256 + t) * 32 + p] = 0;
        return;
    }
    __shared__ float px[512];
    __shared__ float k1[256];
    for (int i = t; i < 512; i += 256) px[i] = proxy[((long)b * 512 + i) * 19 + p];
    __syncthreads();
    float aK = 0.f, aV = 0.f;
    const float* wk1r = wk1 + (long)t * 512;
    const float* wvr  = wv  + (long)t * 512;
    #pragma unroll 8
    for (int c = 0; c < 512; ++c) { aK += wk1r[c] * px[c]; aV += wvr[c] * px[c]; }
    float k1v = fmaxf(aK * (INV_STD * gk1[t]) + bk1[t], 0.f);
    float vv  = fmaxf(aV * (INV_STD * gv[t])  + bv[t],  0.f);
    k1[t] = k1v;
    VB[((long)b * 256 + t) * 32 + p] = f2bf(vv);
    __syncthreads();
    float a2 = 0.f;
    const float* wk2r = wk2 + (long)t * 256;
    #pragma unroll 8
    for (int c = 0; c < 256; ++c) a2 += wk2r[c] * k1[c];
    KB[((long)b * 32 + p) * 256 + t] = f2bf(fmaxf(a2 * (INV_STD * gk2[t]) + bk2[t], 0.f));
}

// ---------------- fused GEMM1: reads x (channel-major f32) directly ----------------
// out[pix][ch] = relu( x[:,pix]·W1[ch,:] + b[ch] ).  BM=64 pix, BN=256 ch, K=512, BK=64, 4 waves.
// x-tile staged to LDS in tr-subtiled layout [pix/16][c/4][c&3][pix&15]; A-frags via ds_read_b64_tr_b16.
// K order within each 32-chunk is sigma-permuted; W (B-operand) pre-permuted by wconv_perm.
__global__ __launch_bounds__(256) void gemm1_x(
    const float* __restrict__ X,     // (B,512,16384)
    const u16* __restrict__ W,       // (256,512) bf16, K-permuted
    const float* __restrict__ bias,
    u16* __restrict__ out)           // (B*HW,256)
{
    __shared__ __align__(16) u16 xs[64 * 64];    //  8 KB, subtiled
    __shared__ __align__(16) u16 lB[256 * 64];   // 32 KB
    int t = threadIdx.x, lane = t & 63, w = t >> 6;
    int l16 = lane & 15, hi = lane >> 4;
    long m0 = (long)blockIdx.x * 64;
    int b = (int)(m0 >> 14);
    int pixg = (int)(m0 & 16383);
    const float* xb = X + (long)b * 512 * 16384 + pixg;
    int rA = lane >> 3, cA = (lane & 7) << 3;
    int ca = t >> 4;       // channel within 16-group
    int aa = t & 15;       // pixel quad
    unsigned trb = lds_off(&xs[hi * 64 + l16]);
    f32x4 acc[4][4] = {};
    float4 xr0, xr1, xr2, xr3;
    {
        const float* p0 = xb + (long)ca * 16384 + aa * 4;
        xr0 = *(const float4*)(p0);
        xr1 = *(const float4*)(p0 + 16L * 16384);
        xr2 = *(const float4*)(p0 + 32L * 16384);
        xr3 = *(const float4*)(p0 + 48L * 16384);
    }
    for (int kt = 0; kt < 8; ++kt) {
        int k0 = kt << 6;
        #pragma unroll
        for (int j = 0; j < 8; ++j) {            // W tile: 256x64, async
            int q = w * 8 + j;
            gl_lds16(W + (long)(q * 8 + rA) * 512 + k0 + cA, &lB[q * 512]);
        }
        // convert + subtiled write: subtile s=(pix>>4)*16+(c>>2), inner (c&3)*16+(pix&15)
        #define STW(XR, P) { \
            int c = (P) * 16 + ca; \
            ushort4 u; u.x = f2bf(XR.x); u.y = f2bf(XR.y); u.z = f2bf(XR.z); u.w = f2bf(XR.w); \
            *(ushort4*)&xs[((aa >> 2) * 16 + (c >> 2)) * 64 + (c & 3) * 16 + (aa & 3) * 4] = u; }
        STW(xr0, 0) STW(xr1, 1) STW(xr2, 2) STW(xr3, 3)
        #undef STW
        __syncthreads();
        if (kt < 7) {                            // prefetch next K-tile under MFMA phase
            const float* p0 = xb + (long)(k0 + 64 + ca) * 16384 + aa * 4;
            xr0 = *(const float4*)(p0);
            xr1 = *(const float4*)(p0 + 16L * 16384);
            xr2 = *(const float4*)(p0 + 32L * 16384);
            xr3 = *(const float4*)(p0 + 48L * 16384);
        }
        #pragma unroll
        for (int kk = 0; kk < 2; ++kk) {
            bf16x8 bb[4];
            #pragma unroll
            for (int j = 0; j < 4; ++j)
                bb[j] = *(const bf16x8*)&lB[(w * 64 + j * 16 + l16) * 64 + kk * 32 + hi * 8];
            bf16x4 lo[4], hh[4];
            #pragma unroll
            for (int i = 0; i < 4; ++i) {
                unsigned a0 = trb + i * 2048 + kk * 1024;
                lo[i] = tr_read(a0);
                hh[i] = tr_read(a0 + 512);
            }
            asm volatile("s_waitcnt lgkmcnt(0)" ::: "memory");
            __builtin_amdgcn_sched_barrier(0);
            #pragma unroll
            for (int i = 0; i < 4; ++i) {
                bf16x8 a = __builtin_shufflevector(lo[i], hh[i], 0, 1, 2, 3, 4, 5, 6, 7);
                #pragma unroll
                for (int j = 0; j < 4; ++j)
                    acc[i][j] = mfma16(a, bb[j], acc[i][j]);
            }
        }
        __syncthreads();
    }
    float bj[4];
    #pragma unroll
    for (int j = 0; j < 4; ++j) bj[j] = bias[w * 64 + j * 16 + l16];
    #pragma unroll
    for (int i = 0; i < 4; ++i) {
        #pragma unroll
        for (int r = 0; r < 4; ++r) {
            long pix = m0 + i * 16 + hi * 4 + r;
            u16* orow = out + pix * 256;
            #pragma unroll
            for (int j = 0; j < 4; ++j) {
                float v = acc[i][j][r] + bj[j];
                orow[w * 64 + j * 16 + l16] = f2bf(fmaxf(v, 0.f));
            }
        }
    }
}

// ---------------- fused GEMM2 + attention ----------------
__global__ __launch_bounds__(256) void gemm2_attn(
    const u16* __restrict__ A,      // Q1 (B*HW, 256) bf16
    const u16* __restrict__ W,      // W2 (256,256) bf16 (BN-folded)
    const float* __restrict__ bias, // bq2
    const u16* __restrict__ KB,     // (B,32,256) bf16
    const u16* __restrict__ VB,     // (B,256,32) bf16
    u16* __restrict__ CTX)          // (B*HW,256) bf16
{
    __shared__ __align__(16) u16 lA[64 * 64];
    __shared__ __align__(16) u16 lB[256 * 64];
    __shared__ __align__(16) u16 q2s[64 * 264];
    __shared__ __align__(16) u16 atts[64 * 40];
    int t = threadIdx.x, lane = t & 63, w = t >> 6;
    int l16 = lane & 15, hi = lane >> 4;
    long m0 = (long)blockIdx.x * 64;
    int b = (int)(m0 >> 14);
    const int K = 256;
    int rA = lane >> 3, cA = (lane & 7) << 3;
    f32x4 acc[4][4] = {};
    #pragma unroll
    for (int kt = 0; kt < 4; ++kt) {
        int k0 = kt << 6;
        #pragma unroll
        for (int j = 0; j < 2; ++j) {
            int q = w * 2 + j;
            gl_lds16(A + (m0 + q * 8 + rA) * (long)K + k0 + cA, &lA[q * 512]);
        }
        #pragma unroll
        for (int j = 0; j < 8; ++j) {
            int q = w * 8 + j;
            gl_lds16(W + (long)(q * 8 + rA) * K + k0 + cA, &lB[q * 512]);
        }
        __syncthreads();
        #pragma unroll
        for (int kk = 0; kk < 2; ++kk) {
            bf16x8 a[4], bb[4];
            #pragma unroll
            for (int i = 0; i < 4; ++i)
                a[i] = *(const bf16x8*)&lA[(i * 16 + l16) * 64 + kk * 32 + hi * 8];
            #pragma unroll
            for (int j = 0; j < 4; ++j)
                bb[j] = *(const bf16x8*)&lB[(w * 64 + j * 16 + l16) * 64 + kk * 32 + hi * 8];
            #pragma unroll
            for (int i = 0; i < 4; ++i)
                #pragma unroll
                for (int j = 0; j < 4; ++j)
                    acc[i][j] = mfma16(a[i], bb[j], acc[i][j]);
        }
        __syncthreads();
    }
    {
        float bj[4];
        #pragma unroll
        for (int j = 0; j < 4; ++j) bj[j] = bias[w * 64 + j * 16 + l16];
        #pragma unroll
        for (int i = 0; i < 4; ++i)
            #pragma unroll
            for (int r = 0; r < 4; ++r) {
                int pix = i * 16 + hi * 4 + r;
                #pragma unroll
                for (int j = 0; j < 4; ++j) {
                    float v = acc[i][j][r] + bj[j];
                    q2s[pix * 264 + w * 64 + j * 16 + l16] = f2bf(fmaxf(v, 0.f));
                }
            }
    }
    __syncthreads();
    f32x4 s0 = {}, s1 = {};
    #pragma unroll
    for (int ks = 0; ks < 8; ++ks) {
        bf16x8 a = *(const bf16x8*)&q2s[(w * 16 + l16) * 264 + ks * 32 + hi * 8];
        bf16x8 b0 = *(const bf16x8*)&KB[((long)b * 32 + l16) * 256 + ks * 32 + hi * 8];
        bf16x8 b1 = *(const bf16x8*)&KB[((long)b * 32 + 16 + l16) * 256 + ks * 32 + hi * 8];
        s0 = mfma16(a, b0, s0);
        s1 = mfma16(a, b1, s1);
    }
    {
        const float scale = 0.0625f;
        #pragma unroll
        for (int r = 0; r < 4; ++r) {
            float v0 = s0[r] * scale;
            float v1 = s1[r] * scale;
            float mx = fmaxf(v0, v1);
            mx = fmaxf(mx, __shfl_xor(mx, 1));
            mx = fmaxf(mx, __shfl_xor(mx, 2));
            mx = fmaxf(mx, __shfl_xor(mx, 4));
            mx = fmaxf(mx, __shfl_xor(mx, 8));
            float e0 = __expf(v0 - mx);
            float e1 = (l16 < 3) ? __expf(v1 - mx) : 0.f;
            float s = e0 + e1;
            s += __shfl_xor(s, 1);
            s += __shfl_xor(s, 2);
            s += __shfl_xor(s, 4);
            s += __shfl_xor(s, 8);
            float inv = 1.f / s;
            int pix = w * 16 + hi * 4 + r;
            atts[pix * 40 + l16] = f2bf(e0 * inv);
            atts[pix * 40 + 16 + l16] = (l16 < 3) ? f2bf(e1 * inv) : (u16)0;
        }
    }
    __syncthreads();
    {
        f32x4 c4[4][4] = {};
        bf16x8 av[4], bv[4];
        #pragma unroll
        for (int mf = 0; mf < 4; ++mf)
            av[mf] = *(const bf16x8*)&atts[(mf * 16 + l16) * 40 + hi * 8];
        #pragma unroll
        for (int nf = 0; nf < 4; ++nf)
            bv[nf] = *(const bf16x8*)&VB[((long)b * 256 + w * 64 + nf * 16 + l16) * 32 + hi * 8];
        #pragma unroll
        for (int mf = 0; mf < 4; ++mf)
            #pragma unroll
            for (int nf = 0; nf < 4; ++nf)
                c4[mf][nf] = mfma16(av[mf], bv[nf], c4[mf][nf]);
        #pragma unroll
        for (int mf = 0; mf < 4; ++mf) {
            #pragma unroll
            for (int r = 0; r < 4; ++r) {
                long pix = m0 + mf * 16 + hi * 4 + r;
                u16* crow = CTX + pix * 256;
                #pragma unroll
                for (int nf = 0; nf < 4; ++nf)
                    crow[w * 64 + nf * 16 + l16] = f2bf(c4[mf][nf][r]);
            }
        }
    }
}

// ---------------- final GEMM: out[b][ch][pix] = relu( wo[ch,:]·ctx[pix,:] + bo[ch] ) ----------------
__global__ __launch_bounds__(512) void gemm_out(const u16* __restrict__ Wo,
                                                const u16* __restrict__ Ctx,
                                                const float* __restrict__ bias,
                                                float* __restrict__ out) {
    __shared__ __align__(16) u16 lA[256 * 64];
    __shared__ __align__(16) u16 lB[128 * 64];
    int t = threadIdx.x, lane = t & 63, w = t >> 6;
    int wm = w >> 1, wn = w & 1;
    int l16 = lane & 15, hi = lane >> 4;
    int m0 = blockIdx.y * 256;
    int n0 = blockIdx.x * 128;
    int b = blockIdx.z;
    const int K = 256;
    int rA = lane >> 3, cA = (lane & 7) << 3;
    f32x4 acc[4][4] = {};
    #pragma unroll
    for (int kt = 0; kt < 4; ++kt) {
        int k0 = kt << 6;
        #pragma unroll
        for (int j = 0; j < 4; ++j) {
            int q = w * 4 + j;
            gl_lds16(Wo + (long)(m0 + q * 8 + rA) * K + k0 + cA, &lA[q * 512]);
        }
        #pragma unroll
        for (int j = 0; j < 2; ++j) {
            int q = w * 2 + j;
            gl_lds16(Ctx + ((long)b * 16384 + n0 + q * 8 + rA) * K + k0 + cA, &lB[q * 512]);
        }
        __syncthreads();
        #pragma unroll
        for (int kk = 0; kk < 2; ++kk) {
            bf16x8 a[4], bb[4];
            #pragma unroll
            for (int i = 0; i < 4; ++i)
                a[i] = *(const bf16x8*)&lA[(wm * 64 + i * 16 + l16) * 64 + kk * 32 + hi * 8];
            #pragma unroll
            for (int j = 0; j < 4; ++j)
                bb[j] = *(const bf16x8*)&lB[(wn * 64 + j * 16 + l16) * 64 + kk * 32 + hi * 8];
            #pragma unroll
            for (int i = 0; i < 4; ++i)
                #pragma unroll
                for (int j = 0; j < 4; ++j)
                    acc[i][j] = mfma16(a[i], bb[j], acc[i][j]);
        }
        __syncthreads();
    }
    #pragma unroll
    for (int i = 0; i < 4; ++i) {
        #pragma unroll
        for (int r = 0; r < 4; ++r) {
            int ch = m0 + wm * 64 + i * 16 + hi * 4 + r;
            float bc = bias[ch];
            float* orow = out + ((long)b * 512 + ch) * 16384;
            #pragma unroll
            for (int j = 0; j < 4; ++j) {
                int pix = n0 + wn * 64 + j * 16 + l16;
                float v = acc[i][j][r] + bc;
                orow[pix] = fmaxf(v, 0.f);
            }
        }
    }
}

extern "C" void kernel_launch(void* const* d_in, const int* in_sizes, int n_in,
                              void* d_out, int out_size, void* d_ws, size_t ws_size,
                              hipStream_t stream) {
    const float* x    = (const float*)d_in[0];
    const float* prox = (const float*)d_in[1];
    const float* wq1  = (const float*)d_in[2];
    const float* gq1  = (const float*)d_in[3];
    const float* bq1  = (const float*)d_in[4];
    const float* wq2  = (const float*)d_in[5];
    const float* gq2  = (const float*)d_in[6];
    const float* bq2  = (const float*)d_in[7];
    const float* wk1  = (const float*)d_in[8];
    const float* gk1  = (const float*)d_in[9];
    const float* bk1  = (const float*)d_in[10];
    const float* wk2  = (const float*)d_in[11];
    const float* gk2  = (const float*)d_in[12];
    const float* bk2  = (const float*)d_in[13];
    const float* wv   = (const float*)d_in[14];
    const float* gv   = (const float*)d_in[15];
    const float* bv   = (const float*)d_in[16];
    const float* wo   = (const float*)d_in[17];
    const float* go   = (const float*)d_in[18];
    const float* bo   = (const float*)d_in[19];
    float* out = (float*)d_out;

    char* ws = (char*)d_ws;
    u16* Q1   = (u16*)(ws);                      // 64 MB
    u16* CTX  = (u16*)(ws + 67108864LL);         // 64 MB
    u16* KB   = (u16*)(ws + 134217728LL);        // 128 KB
    u16* VB   = KB + 65536;                      // 128 KB
    u16* WQ1B = VB + 65536;
    u16* WQ2B = WQ1B + 131072;
    u16* WOB  = WQ2B + 65536;

    wconv_perm<<<512, 256, 0, stream>>>(wq1, gq1, WQ1B);
    wconv<<<256, 256, 0, stream>>>(wq2, gq2, WQ2B, 256, 256);
    wconv<<<512, 256, 0, stream>>>(wo,  go,  WOB, 512, 256);
    kv_kernel<<<256, 256, 0, stream>>>(prox, wk1, gk1, bk1, wk2, gk2, bk2, wv, gv, bv, KB, VB);
    gemm1_x<<<2048, 256, 0, stream>>>(x, WQ1B, bq1, Q1);
    gemm2_attn<<<2048, 256, 0, stream>>>(Q1, WQ2B, bq2, KB, VB, CTX);
    gemm_out<<<dim3(128, 2, 8), 512, 0, stream>>>(WOB, CTX, bo, out);
}

// Round 4
// 266.926 us; speedup vs baseline: 2.2346x; 1.0931x over previous
//
#include <hip/hip_runtime.h>

#define INV_STD 0.9999950000374997f

typedef unsigned short u16;
typedef __bf16 bf16x8 __attribute__((ext_vector_type(8)));
typedef __bf16 bf16x4 __attribute__((ext_vector_type(4)));
typedef float f32x4 __attribute__((ext_vector_type(4)));

__device__ __forceinline__ u16 f2bf(float f) {
    unsigned int u = __float_as_uint(f);
    u += 0x7fffu + ((u >> 16) & 1u);   // RNE
    return (u16)(u >> 16);
}
__device__ __forceinline__ float bf2f(u16 h) {
    return __uint_as_float(((unsigned int)h) << 16);
}

// async global->LDS, 16B per lane. LDS dest must be wave-uniform base (HW adds lane*16).
__device__ __forceinline__ void gl_lds16(const void* g, void* l) {
    __builtin_amdgcn_global_load_lds(
        (const __attribute__((address_space(1))) unsigned int*)(unsigned long long)g,
        (__attribute__((address_space(3))) unsigned int*)(unsigned int)(unsigned long long)l,
        16, 0, 0);
}

__device__ __forceinline__ f32x4 mfma16(bf16x8 a, bf16x8 b, f32x4 c) {
    return __builtin_amdgcn_mfma_f32_16x16x32_bf16(a, b, c, 0, 0, 0);
}

__device__ __forceinline__ unsigned lds_off(const void* p) {
    return (unsigned)(unsigned long long)p;
}

// hardware transpose read: lane reads 4 bf16 at byte addr +0,+32,+64,+96
__device__ __forceinline__ bf16x4 tr_read(unsigned addr) {
    bf16x4 r;
    asm volatile("ds_read_b64_tr_b16 %0, %1" : "=v"(r) : "v"(addr));
    return r;
}

// ---------------- weight convert: dst = bf16(W * (INV_STD*gamma[row])) ----------------
__global__ void wconv(const float* __restrict__ W, const float* __restrict__ gamma,
                      u16* __restrict__ dst, int O, int C) {
    long i = (long)blockIdx.x * 256 + threadIdx.x;
    if (i < (long)O * C) {
        int o = (int)(i / C);
        dst[i] = f2bf(W[i] * (INV_STD * gamma[o]));
    }
}

// ---------------- weight convert + K-permute (sigma within each 32-group), C=512 ----------------
__global__ void wconv_perm(const float* __restrict__ W, const float* __restrict__ gamma,
                           u16* __restrict__ dst) {
    long i = (long)blockIdx.x * 256 + threadIdx.x;   // 256*512 total
    int o = (int)(i >> 9);
    int q = (int)(i & 511);
    int r = q & 31;
    int src = (q & ~31) + ((r >> 3) & 3) * 4 + (r & 3) + ((r >> 2) & 1) * 16;
    dst[i] = f2bf(W[(long)o * 512 + src] * (INV_STD * gamma[o]));
}

// ---------------- k/v path (tiny): one block per (b,p); p in [0,32) with zero-padding ----------------
__global__ __launch_bounds__(256) void kv_kernel(
    const float* __restrict__ proxy,                       // (B,512,19)
    const float* __restrict__ wk1, const float* __restrict__ gk1, const float* __restrict__ bk1,
    const float* __restrict__ wk2, const float* __restrict__ gk2, const float* __restrict__ bk2,
    const float* __restrict__ wv,  const float* __restrict__ gv,  const float* __restrict__ bv,
    u16* __restrict__ KB,                                  // (B,32,256) bf16, rows 19..31 zero
    u16* __restrict__ VB)                                  // (B,256,32) bf16, cols 19..31 zero
{
    int b = blockIdx.x >> 5, p = blockIdx.x & 31;
    int t = threadIdx.x;
    if (p >= 19) {
        KB[((long)b * 32 + p) * 256 + t] = 0;
        VB[((long)b * 256 + t) * 32 + p] = 0;
        return;
    }
    __shared__ float px[512];
    __shared__ float k1[256];
    for (int i = t; i < 512; i += 256) px[i] = proxy[((long)b * 512 + i) * 19 + p];
    __syncthreads();
    float aK = 0.f, aV = 0.f;
    const float* wk1r = wk1 + (long)t * 512;
    const float* wvr  = wv  + (long)t * 512;
    #pragma unroll 8
    for (int c = 0; c < 512; ++c) { aK += wk1r[c] * px[c]; aV += wvr[c] * px[c]; }
    float k1v = fmaxf(aK * (INV_STD * gk1[t]) + bk1[t], 0.f);
    float vv  = fmaxf(aV * (INV_STD * gv[t])  + bv[t],  0.f);
    k1[t] = k1v;
    VB[((long)b * 256 + t) * 32 + p] = f2bf(vv);
    __syncthreads();
    float a2 = 0.f;
    const float* wk2r = wk2 + (long)t * 256;
    #pragma unroll 8
    for (int c = 0; c < 256; ++c) a2 += wk2r[c] * k1[c];
    KB[((long)b * 32 + p) * 256 + t] = f2bf(fmaxf(a2 * (INV_STD * gk2[t]) + bk2[t], 0.f));
}

// ---------------- fused GEMM1: reads x (channel-major f32) directly ----------------
__global__ __launch_bounds__(256) void gemm1_x(
    const float* __restrict__ X,     // (B,512,16384)
    const u16* __restrict__ W,       // (256,512) bf16, K-permuted
    const float* __restrict__ bias,
    u16* __restrict__ out)           // (B*HW,256)
{
    __shared__ __align__(16) u16 xs[64 * 64];    //  8 KB, subtiled
    __shared__ __align__(16) u16 lB[256 * 64];   // 32 KB
    int t = threadIdx.x, lane = t & 63, w = t >> 6;
    int l16 = lane & 15, hi = lane >> 4;
    long m0 = (long)blockIdx.x * 64;
    int b = (int)(m0 >> 14);
    int pixg = (int)(m0 & 16383);
    const float* xb = X + (long)b * 512 * 16384 + pixg;
    int rA = lane >> 3, cA = (lane & 7) << 3;
    int ca = t >> 4;       // channel within 16-group
    int aa = t & 15;       // pixel quad
    unsigned trb = lds_off(&xs[hi * 64 + l16]);
    f32x4 acc[4][4] = {};
    float4 xr0, xr1, xr2, xr3;
    {
        const float* p0 = xb + (long)ca * 16384 + aa * 4;
        xr0 = *(const float4*)(p0);
        xr1 = *(const float4*)(p0 + 16L * 16384);
        xr2 = *(const float4*)(p0 + 32L * 16384);
        xr3 = *(const float4*)(p0 + 48L * 16384);
    }
    for (int kt = 0; kt < 8; ++kt) {
        int k0 = kt << 6;
        #pragma unroll
        for (int j = 0; j < 8; ++j) {
            int q = w * 8 + j;
            gl_lds16(W + (long)(q * 8 + rA) * 512 + k0 + cA, &lB[q * 512]);
        }
        #define STW(XR, P) { \
            int c = (P) * 16 + ca; \
            ushort4 u; u.x = f2bf(XR.x); u.y = f2bf(XR.y); u.z = f2bf(XR.z); u.w = f2bf(XR.w); \
            *(ushort4*)&xs[((aa >> 2) * 16 + (c >> 2)) * 64 + (c & 3) * 16 + (aa & 3) * 4] = u; }
        STW(xr0, 0) STW(xr1, 1) STW(xr2, 2) STW(xr3, 3)
        #undef STW
        __syncthreads();
        if (kt < 7) {
            const float* p0 = xb + (long)(k0 + 64 + ca) * 16384 + aa * 4;
            xr0 = *(const float4*)(p0);
            xr1 = *(const float4*)(p0 + 16L * 16384);
            xr2 = *(const float4*)(p0 + 32L * 16384);
            xr3 = *(const float4*)(p0 + 48L * 16384);
        }
        #pragma unroll
        for (int kk = 0; kk < 2; ++kk) {
            bf16x8 bb[4];
            #pragma unroll
            for (int j = 0; j < 4; ++j)
                bb[j] = *(const bf16x8*)&lB[(w * 64 + j * 16 + l16) * 64 + kk * 32 + hi * 8];
            bf16x4 lo[4], hh[4];
            #pragma unroll
            for (int i = 0; i < 4; ++i) {
                unsigned a0 = trb + i * 2048 + kk * 1024;
                lo[i] = tr_read(a0);
                hh[i] = tr_read(a0 + 512);
            }
            asm volatile("s_waitcnt lgkmcnt(0)" ::: "memory");
            __builtin_amdgcn_sched_barrier(0);
            #pragma unroll
            for (int i = 0; i < 4; ++i) {
                bf16x8 a = __builtin_shufflevector(lo[i], hh[i], 0, 1, 2, 3, 4, 5, 6, 7);
                #pragma unroll
                for (int j = 0; j < 4; ++j)
                    acc[i][j] = mfma16(a, bb[j], acc[i][j]);
            }
        }
        __syncthreads();
    }
    float bj[4];
    #pragma unroll
    for (int j = 0; j < 4; ++j) bj[j] = bias[w * 64 + j * 16 + l16];
    #pragma unroll
    for (int i = 0; i < 4; ++i) {
        #pragma unroll
        for (int r = 0; r < 4; ++r) {
            long pix = m0 + i * 16 + hi * 4 + r;
            u16* orow = out + pix * 256;
            #pragma unroll
            for (int j = 0; j < 4; ++j) {
                float v = acc[i][j][r] + bj[j];
                orow[w * 64 + j * 16 + l16] = f2bf(fmaxf(v, 0.f));
            }
        }
    }
}

// ---------------- fused GEMM2 + attention + output projection ----------------
// Per block: 64 pixels. q2 -> sim -> softmax -> ctx (LDS) -> out = relu(Wo·ctx + bo) fp32 channel-major.
__global__ __launch_bounds__(256) void gemm2_attn_out(
    const u16* __restrict__ A,      // Q1 (B*HW, 256) bf16
    const u16* __restrict__ W,      // W2 (256,256) bf16 (BN-folded)
    const float* __restrict__ bias, // bq2
    const u16* __restrict__ KB,     // (B,32,256) bf16
    const u16* __restrict__ VB,     // (B,256,32) bf16
    const u16* __restrict__ Wo,     // (512,256) bf16 (BN-folded)
    const float* __restrict__ obias,// bo
    float* __restrict__ out)        // (B,512,16384) fp32
{
    __shared__ __align__(16) u16 lA[64 * 64];     //  8 KB
    __shared__ __align__(16) u16 lB[256 * 64];    // 32 KB
    __shared__ __align__(16) u16 q2s[64 * 264];   // 33 KB; q2 tile, later reused as ctx tile
    __shared__ __align__(16) u16 atts[64 * 40];   //  5 KB
    int t = threadIdx.x, lane = t & 63, w = t >> 6;
    int l16 = lane & 15, hi = lane >> 4;
    long m0 = (long)blockIdx.x * 64;
    int b = (int)(m0 >> 14);
    int pixg = (int)(m0 & 16383);
    const int K = 256;
    int rA = lane >> 3, cA = (lane & 7) << 3;
    // ---- phase 1: GEMM2, q2 = relu(q1 · W2^T + b) ----
    {
        f32x4 acc[4][4] = {};
        #pragma unroll
        for (int kt = 0; kt < 4; ++kt) {
            int k0 = kt << 6;
            #pragma unroll
            for (int j = 0; j < 2; ++j) {
                int q = w * 2 + j;
                gl_lds16(A + (m0 + q * 8 + rA) * (long)K + k0 + cA, &lA[q * 512]);
            }
            #pragma unroll
            for (int j = 0; j < 8; ++j) {
                int q = w * 8 + j;
                gl_lds16(W + (long)(q * 8 + rA) * K + k0 + cA, &lB[q * 512]);
            }
            __syncthreads();
            #pragma unroll
            for (int kk = 0; kk < 2; ++kk) {
                bf16x8 a[4], bb[4];
                #pragma unroll
                for (int i = 0; i < 4; ++i)
                    a[i] = *(const bf16x8*)&lA[(i * 16 + l16) * 64 + kk * 32 + hi * 8];
                #pragma unroll
                for (int j = 0; j < 4; ++j)
                    bb[j] = *(const bf16x8*)&lB[(w * 64 + j * 16 + l16) * 64 + kk * 32 + hi * 8];
                #pragma unroll
                for (int i = 0; i < 4; ++i)
                    #pragma unroll
                    for (int j = 0; j < 4; ++j)
                        acc[i][j] = mfma16(a[i], bb[j], acc[i][j]);
            }
            __syncthreads();
        }
        float bj[4];
        #pragma unroll
        for (int j = 0; j < 4; ++j) bj[j] = bias[w * 64 + j * 16 + l16];
        #pragma unroll
        for (int i = 0; i < 4; ++i)
            #pragma unroll
            for (int r = 0; r < 4; ++r) {
                int pix = i * 16 + hi * 4 + r;
                #pragma unroll
                for (int j = 0; j < 4; ++j) {
                    float v = acc[i][j][r] + bj[j];
                    q2s[pix * 264 + w * 64 + j * 16 + l16] = f2bf(fmaxf(v, 0.f));
                }
            }
    }
    __syncthreads();
    // ---- phase 2: sim = q2 · KB^T, softmax -> atts (bf16) ----
    {
        f32x4 s0 = {}, s1 = {};
        #pragma unroll
        for (int ks = 0; ks < 8; ++ks) {
            bf16x8 a = *(const bf16x8*)&q2s[(w * 16 + l16) * 264 + ks * 32 + hi * 8];
            bf16x8 b0 = *(const bf16x8*)&KB[((long)b * 32 + l16) * 256 + ks * 32 + hi * 8];
            bf16x8 b1 = *(const bf16x8*)&KB[((long)b * 32 + 16 + l16) * 256 + ks * 32 + hi * 8];
            s0 = mfma16(a, b0, s0);
            s1 = mfma16(a, b1, s1);
        }
        const float scale = 0.0625f;
        #pragma unroll
        for (int r = 0; r < 4; ++r) {
            float v0 = s0[r] * scale;
            float v1 = s1[r] * scale;
            float mx = fmaxf(v0, v1);
            mx = fmaxf(mx, __shfl_xor(mx, 1));
            mx = fmaxf(mx, __shfl_xor(mx, 2));
            mx = fmaxf(mx, __shfl_xor(mx, 4));
            mx = fmaxf(mx, __shfl_xor(mx, 8));
            float e0 = __expf(v0 - mx);
            float e1 = (l16 < 3) ? __expf(v1 - mx) : 0.f;
            float s = e0 + e1;
            s += __shfl_xor(s, 1);
            s += __shfl_xor(s, 2);
            s += __shfl_xor(s, 4);
            s += __shfl_xor(s, 8);
            float inv = 1.f / s;
            int pix = w * 16 + hi * 4 + r;
            atts[pix * 40 + l16] = f2bf(e0 * inv);
            atts[pix * 40 + 16 + l16] = (l16 < 3) ? f2bf(e1 * inv) : (u16)0;
        }
    }
    __syncthreads();     // all sim reads of q2s complete; q2s reusable as ctx
    // ---- phase 3: ctx = att · VB^T -> ctxs (= q2s buffer) ----
    {
        f32x4 c4[4][4] = {};
        bf16x8 av[4], bv[4];
        #pragma unroll
        for (int mf = 0; mf < 4; ++mf)
            av[mf] = *(const bf16x8*)&atts[(mf * 16 + l16) * 40 + hi * 8];
        #pragma unroll
        for (int nf = 0; nf < 4; ++nf)
            bv[nf] = *(const bf16x8*)&VB[((long)b * 256 + w * 64 + nf * 16 + l16) * 32 + hi * 8];
        #pragma unroll
        for (int mf = 0; mf < 4; ++mf)
            #pragma unroll
            for (int nf = 0; nf < 4; ++nf)
                c4[mf][nf] = mfma16(av[mf], bv[nf], c4[mf][nf]);
        #pragma unroll
        for (int mf = 0; mf < 4; ++mf)
            #pragma unroll
            for (int r = 0; r < 4; ++r) {
                int pix = mf * 16 + hi * 4 + r;
                #pragma unroll
                for (int nf = 0; nf < 4; ++nf)
                    q2s[pix * 264 + w * 64 + nf * 16 + l16] = f2bf(c4[mf][nf][r]);
            }
    }
    // ---- phase 4: out = relu(Wo · ctx^T + bo); M=512 in 2 halves of 256, N=64 pix, K=256 ----
    #pragma unroll
    for (int half = 0; half < 2; ++half) {
        f32x4 acc2[4][4] = {};
        __syncthreads();    // half 0: ctx writes visible + lB free; half 1: lB free
        #pragma unroll
        for (int kt = 0; kt < 4; ++kt) {
            int k0 = kt << 6;
            #pragma unroll
            for (int j = 0; j < 8; ++j) {
                int q = w * 8 + j;
                gl_lds16(Wo + (long)(half * 256 + q * 8 + rA) * K + k0 + cA, &lB[q * 512]);
            }
            __syncthreads();
            #pragma unroll
            for (int kk = 0; kk < 2; ++kk) {
                bf16x8 a[4], bb[4];
                #pragma unroll
                for (int i = 0; i < 4; ++i)
                    a[i] = *(const bf16x8*)&lB[(w * 64 + i * 16 + l16) * 64 + kk * 32 + hi * 8];
                #pragma unroll
                for (int j = 0; j < 4; ++j)
                    bb[j] = *(const bf16x8*)&q2s[(j * 16 + l16) * 264 + k0 + kk * 32 + hi * 8];
                #pragma unroll
                for (int i = 0; i < 4; ++i)
                    #pragma unroll
                    for (int j = 0; j < 4; ++j)
                        acc2[i][j] = mfma16(a[i], bb[j], acc2[i][j]);
            }
            __syncthreads();
        }
        float* outb = out + ((long)b * 512 + half * 256) * 16384 + pixg;
        #pragma unroll
        for (int i = 0; i < 4; ++i)
            #pragma unroll
            for (int r = 0; r < 4; ++r) {
                int ch = w * 64 + i * 16 + hi * 4 + r;
                float bc = obias[half * 256 + ch];
                float* orow = outb + (long)ch * 16384;
                #pragma unroll
                for (int j = 0; j < 4; ++j)
                    orow[j * 16 + l16] = fmaxf(acc2[i][j][r] + bc, 0.f);
            }
    }
}

extern "C" void kernel_launch(void* const* d_in, const int* in_sizes, int n_in,
                              void* d_out, int out_size, void* d_ws, size_t ws_size,
                              hipStream_t stream) {
    const float* x    = (const float*)d_in[0];
    const float* prox = (const float*)d_in[1];
    const float* wq1  = (const float*)d_in[2];
    const float* gq1  = (const float*)d_in[3];
    const float* bq1  = (const float*)d_in[4];
    const float* wq2  = (const float*)d_in[5];
    const float* gq2  = (const float*)d_in[6];
    const float* bq2  = (const float*)d_in[7];
    const float* wk1  = (const float*)d_in[8];
    const float* gk1  = (const float*)d_in[9];
    const float* bk1  = (const float*)d_in[10];
    const float* wk2  = (const float*)d_in[11];
    const float* gk2  = (const float*)d_in[12];
    const float* bk2  = (const float*)d_in[13];
    const float* wv   = (const float*)d_in[14];
    const float* gv   = (const float*)d_in[15];
    const float* bv   = (const float*)d_in[16];
    const float* wo   = (const float*)d_in[17];
    const float* go   = (const float*)d_in[18];
    const float* bo   = (const float*)d_in[19];
    float* out = (float*)d_out;

    char* ws = (char*)d_ws;
    u16* Q1   = (u16*)(ws);                      // 64 MB
    u16* KB   = (u16*)(ws + 67108864LL);         // 128 KB
    u16* VB   = KB + 65536;                      // 128 KB
    u16* WQ1B = VB + 65536;
    u16* WQ2B = WQ1B + 131072;
    u16* WOB  = WQ2B + 65536;

    wconv_perm<<<512, 256, 0, stream>>>(wq1, gq1, WQ1B);
    wconv<<<256, 256, 0, stream>>>(wq2, gq2, WQ2B, 256, 256);
    wconv<<<512, 256, 0, stream>>>(wo,  go,  WOB, 512, 256);
    kv_kernel<<<256, 256, 0, stream>>>(prox, wk1, gk1, bk1, wk2, gk2, bk2, wv, gv, bv, KB, VB);
    gemm1_x<<<2048, 256, 0, stream>>>(x, WQ1B, bq1, Q1);
    gemm2_attn_out<<<2048, 256, 0, stream>>>(Q1, WQ2B, bq2, KB, VB, WOB, bo, out);
}